// Round 17
// baseline (114.562 us; speedup 1.0000x reference)
//
#include <hip/hip_runtime.h>

typedef __bf16 bf16x8 __attribute__((ext_vector_type(8)));
typedef float f32x4 __attribute__((ext_vector_type(4)));

#define TWO_LOG2E 2.88539008177792681f   // 2*log2(e): exp(2x) = exp2(x*TWO_LOG2E)

#define GLOADLDS16(g, l) __builtin_amdgcn_global_load_lds(                     \
    (const __attribute__((address_space(1))) void*)(g),                        \
    (__attribute__((address_space(3))) void*)(l), 16, 0, 0)

__device__ __forceinline__ unsigned f2bf(float f) {
    unsigned u = __float_as_uint(f);
    return (u + 0x7FFFu + ((u >> 16) & 1u)) >> 16;   // RNE
}

// ---------------- kernel 1: row-normalize z=[z1;z2] -> bf16 zn[8192][256] ---------------
__global__ void __launch_bounds__(256) normalize_kernel(
    const float* __restrict__ z1, const float* __restrict__ z2,
    unsigned short* __restrict__ zn, float* __restrict__ S, float* __restrict__ out)
{
    if (blockIdx.x < 32) S[(blockIdx.x << 8) + threadIdx.x] = 0.f;
    if (blockIdx.x == 32 && threadIdx.x == 0) out[0] = 0.f;

    const int wave = threadIdx.x >> 6, lane = threadIdx.x & 63;
    const int row = (blockIdx.x << 2) + wave;               // 2048 blocks * 4 rows
    const float* src = (row < 4096) ? (z1 + row * 256) : (z2 + (row - 4096) * 256);
    float4 v = ((const float4*)src)[lane];                  // 64 lanes * 4 = 256
    float ss = v.x * v.x + v.y * v.y + v.z * v.z + v.w * v.w;
#pragma unroll
    for (int m = 32; m > 0; m >>= 1) ss += __shfl_xor(ss, m, 64);
    float sc = 1.0f / fmaxf(sqrtf(ss), 1e-8f);
    uint2 w;
    w.x = f2bf(v.x * sc) | (f2bf(v.y * sc) << 16);
    w.y = f2bf(v.z * sc) | (f2bf(v.w * sc) << 16);
    *(uint2*)(zn + row * 256 + (lane << 2)) = w;
}

// ---------------- kernel 2: R0 wave-autonomous chassis + symmetric triangle ------------
// Key comparison after 7 structural nulls: R0 (barrier-free 1-wave blocks, private LDS
// ring, depth-3 vmcnt(12)) did FULL work in 43.8us (38% matrix util); the R8 lockstep
// lineage does HALF work in ~38us (26%). Autonomous waves overlap pipes; barrier
// convoys serialize them. R16 = R0 body verbatim + upper-triangle symmetry:
//   job = 64 rows x 256 cols (8 col-chunks x 4 k-chunks = 32 chunks of 32c x 64k).
//   Keep (r,c2) iff r <= 4*c2+3: strict-upper (r<4c2): all chunks, scatter rows AND
//   mirror cols; straddle (k=r-4c2 in 0..3): skip chunks cc<2k (fully below diag),
//   element-mask chunks cc in {2k,2k+1} (col>=row -> rowsum incl self-term, col>row ->
//   mirror colsum; col<row -> nothing, covered by that pair's upper job).
//   2112 jobs (~2048 wave-slots); job order reversed so short straddle jobs are the
//   overhang tail. Coverage: every unordered pair hits S exactly once (verified).
// Staging/sync = R0 proven: stage chunk m+3 (4x gloadlds, 128B-contiguous rows, XOR
// swizzle), wait counted `s_waitcnt vmcnt(12)` (=3 chunks in flight), consume; tail
// drains 12->8->4->0. Ring = 4 private buffers, no barriers anywhere.
__global__ void __launch_bounds__(64, 2) simexp_kernel(
    const unsigned short* __restrict__ zn, float* __restrict__ S)
{
    __shared__ __align__(16) unsigned short Bs[4][2048];    // wave-private 16KB ring

    const int lane = threadIdx.x;
    const int q = lane >> 4, n16 = lane & 15;

    const int job = 2111 - blockIdx.x;          // reverse: short straddle jobs last
    int c2 = 0, rem = job;
    while (rem >= (c2 << 2) + 4) { rem -= (c2 << 2) + 4; ++c2; }   // <=32 iters, uniform
    const int r = rem;                          // row-strip 0..4*c2+3
    const int k = r - (c2 << 2);                // >=0 iff diagonal-straddle
    const bool straddle = (k >= 0);
    const int cc0 = straddle ? (k << 1) : 0;    // first computed col-chunk
    const int rowBase = r << 6;
    const int colRun  = c2 << 8;

    // A: 64 rows x K=256 in registers (frag: row=n16, k=q*8 within 32-elem step)
    bf16x8 a[4][8];
#pragma unroll
    for (int rt = 0; rt < 4; ++rt)
#pragma unroll
        for (int ks = 0; ks < 8; ++ks)
            a[rt][ks] = *(const bf16x8*)(zn + ((rowBase + (rt << 4) + n16) << 8)
                                            + (ks << 5) + (q << 3));

    // stage chunk m (col-chunk m>>2, k-chunk m&3) into ring buffer m&3
    auto stage = [&](int m) {
        const int colBase = colRun + ((m >> 2) << 5);
        const int koff = (m & 3) << 6;
        unsigned short* base = &Bs[m & 3][0];
#pragma unroll
        for (int p = 0; p < 4; ++p) {
            int s = (p << 6) + lane;            // 16B slot 0..255
            int c = s >> 3, d = s & 7;          // 8 consecutive lanes per row -> 128B
            int k8 = d ^ (c & 7);               // XOR swizzle (conflict-free b128 reads)
            GLOADLDS16(zn + ((colBase + c) << 8) + koff + (k8 << 3), base + (s << 3));
        }
    };

    float rs[4][4];
#pragma unroll
    for (int i = 0; i < 4; ++i)
#pragma unroll
        for (int j = 0; j < 4; ++j) rs[i][j] = 0.f;

    f32x4 acc[4][2];
    auto consume = [&](int kc) {                // buffer kc (m&3==kc since m=cc*4+kc)
        const unsigned short* bb = &Bs[kc][0];
#pragma unroll
        for (int ks = 0; ks < 2; ++ks) {
            bf16x8 bf[2];
#pragma unroll
            for (int ct = 0; ct < 2; ++ct) {
                int c  = (ct << 4) + n16;               // col 0..31
                int k8 = ((ks << 2) + q) ^ (c & 7);     // swizzled chunk
                bf[ct] = *(const bf16x8*)(bb + (((c << 3) + k8) << 3));
            }
#pragma unroll
            for (int rt = 0; rt < 4; ++rt)
#pragma unroll
                for (int ct = 0; ct < 2; ++ct)
                    acc[rt][ct] = __builtin_amdgcn_mfma_f32_16x16x32_bf16(
                        a[rt][(kc << 1) + ks], bf[ct], acc[rt][ct], 0, 0, 0);
        }
    };
    auto zacc = [&]() {
#pragma unroll
        for (int rt = 0; rt < 4; ++rt)
#pragma unroll
            for (int ct = 0; ct < 2; ++ct) acc[rt][ct] = (f32x4){0.f, 0.f, 0.f, 0.f};
    };
    // epilogue: rows -> rs (col>=row when masked); mirror cols -> q-reduce + atomicAdd
    // (col>row when masked). C/D layout: col=n16 within ct-tile, row=q*4+rr.
    auto epiC = [&](int cc, bool msk) {
        float cs[2] = {0.f, 0.f};
        const int colC = colRun + (cc << 5);
#pragma unroll
        for (int rt = 0; rt < 4; ++rt)
#pragma unroll
            for (int ct = 0; ct < 2; ++ct) {
                const int col = colC + (ct << 4) + n16;
                const int rw0 = rowBase + (rt << 4) + (q << 2);
#pragma unroll
                for (int rr = 0; rr < 4; ++rr) {
                    float e = __builtin_amdgcn_exp2f(acc[rt][ct][rr] * TWO_LOG2E);
                    if (msk) {
                        int row = rw0 + rr;
                        rs[rt][rr] += (col >= row) ? e : 0.f;
                        cs[ct]     += (col >  row) ? e : 0.f;
                    } else {
                        rs[rt][rr] += e;
                        cs[ct] += e;
                    }
                }
            }
#pragma unroll
        for (int ct = 0; ct < 2; ++ct) {
            float s = cs[ct];
            s += __shfl_xor(s, 16, 64);         // reduce over q
            s += __shfl_xor(s, 32, 64);
            if (lane < 16) atomicAdd(&S[colC + (ct << 4) + n16], s);
        }
    };

    // prologue: depth-3 (chunks m0, m0+1, m0+2; m0 = cc0*4 so buffers 0,1,2)
    const int m0 = cc0 << 2;
    stage(m0); stage(m0 + 1); stage(m0 + 2);

    for (int cc = cc0; cc < 7; ++cc) {          // intervals m=cc*4+kc, m=m0..27
        zacc();
        const bool msk = straddle && (cc < (k << 1) + 2);   // wave-uniform
#pragma unroll
        for (int kc = 0; kc < 4; ++kc) {
            stage((cc << 2) + kc + 3);          // stages m0+3..30
            asm volatile("s_waitcnt vmcnt(12)" ::: "memory");  // chunk m complete
            consume(kc);
        }
        epiC(cc, msk);
    }
    // peeled tail cc=7: chunks 28..31 (stage 31 then drain 12->8->4->0)
    zacc();
    stage(31);
    asm volatile("s_waitcnt vmcnt(12)" ::: "memory");
    consume(0);
    asm volatile("s_waitcnt vmcnt(8)" ::: "memory");
    consume(1);
    asm volatile("s_waitcnt vmcnt(4)" ::: "memory");
    consume(2);
    asm volatile("s_waitcnt vmcnt(0)" ::: "memory");
    consume(3);
    epiC(7, straddle && (7 < (k << 1) + 2));    // masked only for k=3

    // row flush (C/D layout: col=n16, row=q*4+r); wave covers 64 rows
#pragma unroll
    for (int rt = 0; rt < 4; ++rt)
#pragma unroll
        for (int rr = 0; rr < 4; ++rr) {
            float s = rs[rt][rr];
            s += __shfl_xor(s, 1, 64);
            s += __shfl_xor(s, 2, 64);
            s += __shfl_xor(s, 4, 64);
            s += __shfl_xor(s, 8, 64);
            if (n16 == 0) atomicAdd(&S[rowBase + (rt << 4) + (q << 2) + rr], s);
        }
}

// ---------------- kernel 3: loss = mean( log(S_i - e^{sim_ii}) - sim_{i,target} ) -------
__global__ void __launch_bounds__(256) finish_kernel(
    const unsigned short* __restrict__ zn, const float* __restrict__ S,
    float* __restrict__ out)
{
    __shared__ float vals[16];
    const int tid = threadIdx.x, lane = tid & 63, wave = tid >> 6;
    const int q = lane >> 4, n16 = lane & 15;
    const int rib = (wave << 2) + q;                // 0..15 rows per block
    const int row = (blockIdx.x << 4) + rib;        // 512 blocks * 16 rows
    const int tar = (row + 4096) & 8191;

    float drr = 0.f, drt = 0.f;
#pragma unroll
    for (int i = 0; i < 4; ++i) {
        int k = (i << 6) + (n16 << 2);
        uint2 ur = *(const uint2*)(zn + (row << 8) + k);
        uint2 ut = *(const uint2*)(zn + (tar << 8) + k);
        float a0 = __uint_as_float(ur.x << 16),  a1 = __uint_as_float(ur.x & 0xFFFF0000u);
        float a2 = __uint_as_float(ur.y << 16),  a3 = __uint_as_float(ur.y & 0xFFFF0000u);
        float b0 = __uint_as_float(ut.x << 16),  b1 = __uint_as_float(ut.x & 0xFFFF0000u);
        float b2 = __uint_as_float(ut.y << 16),  b3 = __uint_as_float(ut.y & 0xFFFF0000u);
        drr += a0 * a0 + a1 * a1 + a2 * a2 + a3 * a3;
        drt += a0 * b0 + a1 * b1 + a2 * b2 + a3 * b3;
    }
#pragma unroll
    for (int m = 1; m <= 8; m <<= 1) {
        drr += __shfl_xor(drr, m, 64);
        drt += __shfl_xor(drt, m, 64);
    }
    if (n16 == 0) {
        float Sv = S[row] - __builtin_amdgcn_exp2f(drr * TWO_LOG2E);  // remove diagonal
        vals[rib] = 0.693147180559945f * __builtin_amdgcn_logf(Sv) - 2.0f * drt;
    }
    __syncthreads();
    if (tid == 0) {
        float s = 0.f;
#pragma unroll
        for (int i = 0; i < 16; ++i) s += vals[i];
        atomicAdd(out, s * (1.0f / 8192.0f));
    }
}

extern "C" void kernel_launch(void* const* d_in, const int* in_sizes, int n_in,
                              void* d_out, int out_size, void* d_ws, size_t ws_size,
                              hipStream_t stream)
{
    const float* z1 = (const float*)d_in[0];
    const float* z2 = (const float*)d_in[1];
    unsigned short* zn = (unsigned short*)d_ws;                              // 4 MB
    float* S = (float*)((char*)d_ws + 8192 * 256 * sizeof(unsigned short));  // 32 KB
    float* out = (float*)d_out;

    normalize_kernel<<<2048, 256, 0, stream>>>(z1, z2, zn, S, out);
    simexp_kernel<<<2112, 64, 0, stream>>>(zn, S);
    finish_kernel<<<512, 256, 0, stream>>>(zn, S, out);
}